// Round 16
// baseline (115.092 us; speedup 1.0000x reference)
//
#include <hip/hip_runtime.h>
#include <stdint.h>

constexpr int T_TOK = 8192;
constexpr int D_DIM = 1024;
constexpr int H_DIM = 2048;
constexpr int E_NUM = 8;

typedef __bf16 bf16x8 __attribute__((ext_vector_type(8)));
typedef float  f32x4  __attribute__((ext_vector_type(4)));

#define FENCE() asm volatile("" ::: "memory")
#define BARRIER() do { FENCE(); __builtin_amdgcn_s_barrier(); FENCE(); } while (0)
#define WAIT_LGKM0() asm volatile("s_waitcnt lgkmcnt(0)" ::: "memory")
#define WAIT_VM(N) asm volatile("s_waitcnt vmcnt(%0)" :: "i"(N) : "memory")

// ==== GEMM1: BOTH operands fp32, staged via global_load_lds, cvt-on-read ====
// A = x fp32 (T,K). B = w_up fp32 (E,N,K). h = bf16(bf16(relu(acc))^2).
// BM=256, BN=256, BK=32, 8 waves, A/B double-buffered (128 KiB).
// One barrier + one WAIT_VM(0) per K-step; stages for step t+1 issued at
// body-top of step t (after the barrier -> prior reader's ds_reads done ->
// cross-wave safe). fp32 rows are 128B/step = full cache lines.
// Swizzle (rule #21, both sides): source granule g ^= row&7; read side same.
__global__ __launch_bounds__(512, 2)
void ggx(const float* __restrict__ X,
         const float* __restrict__ Bw,
         const int* __restrict__ counts,
         unsigned short* __restrict__ Hout) {
  constexpr int K_DIM = D_DIM, N_DIM = H_DIM;
  constexpr int BM = 256, BK = 32, BN = 256;
  constexpr int NT = K_DIM / BK;        // 32
  constexpr int WN = 64, NACC = 4;

  const int tid  = threadIdx.x;
  const int wid  = tid >> 6;
  const int lane = tid & 63;
  const int wr   = wid >> 2;
  const int wc   = wid & 3;

  // XCD swizzle: col-tile pinned per XCD (hardware XCD = linear id % 8)
  const int id = blockIdx.x + gridDim.x * blockIdx.y;
  const int ct = id & 7;
  const int rt = id >> 3;

  int t = rt;
  int e = -1, rowBase = 0, rowsValid = 0;
  {
    int tiles = 0, off = 0;
#pragma unroll
    for (int i = 0; i < E_NUM; ++i) {
      int n  = counts[i];
      int nt = (n + BM - 1) / BM;
      if (e < 0 && t < tiles + nt) {
        e = i;
        int lt = t - tiles;
        rowBase   = off + lt * BM;
        rowsValid = n - lt * BM;
        if (rowsValid > BM) rowsValid = BM;
      }
      tiles += nt; off += n;
    }
  }
  if (e < 0) return;
  const int colBase = ct * BN;

  // LDS: A fp32 dbuf 2x32KB + B fp32 dbuf 2x32KB = 128 KiB
  __shared__ __align__(1024) char lds[4 * BM * 128];
  auto ldsA = [&](int b) -> char* { return lds + b * (BM * 128); };
  auto ldsB = [&](int b) -> char* { return lds + (2 + b) * (BM * 128); };

  const char* gA = (const char*)X + (size_t)rowBase * (K_DIM * 4);
  const char* gB = (const char*)Bw + ((size_t)e * N_DIM + colBase) * (size_t)(K_DIM * 4);

  // stage one fp32 K-step slab (256 rows x 128B): 4 issues/wave
  auto stageA = [&](int buf, int kt) {
#pragma unroll
    for (int j = 0; j < 4; ++j) {
      int row0u = j * 64 + wid * 8;                // wave-uniform
      int r  = row0u + (lane >> 3);
      int sr = (r < rowsValid) ? r : rowsValid - 1;
      int sg = (lane & 7) ^ (r & 7);
      const char* src = gA + (size_t)sr * (K_DIM * 4) + (size_t)kt * 128 + sg * 16;
      __builtin_amdgcn_global_load_lds(
          (const __attribute__((address_space(1))) void*)src,
          (__attribute__((address_space(3))) void*)(ldsA(buf) + row0u * 128),
          16, 0, 0);
    }
  };
  auto stageB = [&](int buf, int kt) {
#pragma unroll
    for (int j = 0; j < 4; ++j) {
      int row0u = j * 64 + wid * 8;
      int r  = row0u + (lane >> 3);
      int sg = (lane & 7) ^ (r & 7);
      const char* src = gB + (size_t)r * (K_DIM * 4) + (size_t)kt * 128 + sg * 16;
      __builtin_amdgcn_global_load_lds(
          (const __attribute__((address_space(1))) void*)src,
          (__attribute__((address_space(3))) void*)(ldsB(buf) + row0u * 128),
          16, 0, 0);
    }
  };

  const int rl = lane & 15;
  const int gh = lane >> 4;

  bf16x8 aF[8], bF[NACC];
  f32x4  accC[8][NACC];
#pragma unroll
  for (int m = 0; m < 8; ++m)
#pragma unroll
    for (int n = 0; n < NACC; ++n) accC[m][n] = (f32x4){0.f, 0.f, 0.f, 0.f};

  // read fp32 frag + convert (v_cvt_pk_bf16_f32 on plain loads -> safe deps)
  auto readF = [&](const char* base, int r) -> bf16x8 {
    const char* rb = base + r * 128;
    f32x4 v0 = *(const f32x4*)(rb + (((2 * gh + 0) ^ (r & 7)) * 16));
    f32x4 v1 = *(const f32x4*)(rb + (((2 * gh + 1) ^ (r & 7)) * 16));
    union { __bf16 b[8]; bf16x8 v; } u;
#pragma unroll
    for (int p = 0; p < 4; ++p) {
      u.b[p]     = (__bf16)v0[p];
      u.b[4 + p] = (__bf16)v1[p];
    }
    return u.v;
  };

  // ---- prologue: step 0 staged; loop drains at top
  stageA(0, 0); stageB(0, 0);

  for (int t2 = 0; t2 < NT; ++t2) {
    WAIT_VM(0);                          // step t2's 8 issues complete
    BARRIER();                           // publish buf[t2&1]
    const int ks = (t2 + 1 < NT) ? t2 + 1 : NT - 1;
    const int bn = (t2 + 1) & 1, bc = t2 & 1;
    stageA(bn, ks);                      // prior reader drained pre-barrier
    stageB(bn, ks);
#pragma unroll
    for (int m = 0; m < 8; ++m) aF[m] = readF(ldsA(bc), wr * 128 + m * 16 + rl);
#pragma unroll
    for (int n = 0; n < NACC; ++n) bF[n] = readF(ldsB(bc), wc * WN + n * 16 + rl);
    WAIT_LGKM0();
    __builtin_amdgcn_s_setprio(1);
#pragma unroll
    for (int m = 0; m < 8; ++m)
#pragma unroll
      for (int n = 0; n < NACC; ++n)
        accC[m][n] = __builtin_amdgcn_mfma_f32_16x16x32_bf16(
            aF[m], bF[n], accC[m][n], 0, 0, 0);
    __builtin_amdgcn_s_setprio(0);
  }
  WAIT_VM(0);                            // drain tail stages (LDS-dest only)

  // ---- epilogue: h = bf16(bf16(relu(acc))^2)
  const int rB0 = wr * 128 + gh * 4;
  const int cB0 = colBase + wc * WN + rl;
#pragma unroll
  for (int m = 0; m < 8; ++m) {
#pragma unroll
    for (int n = 0; n < NACC; ++n) {
#pragma unroll
      for (int j = 0; j < 4; ++j) {
        int r = rB0 + m * 16 + j;
        if (r < rowsValid) {
          size_t idx = (size_t)(rowBase + r) * N_DIM + (cB0 + n * 16);
          float v = accC[m][n][j];
          float rv = v > 0.f ? v : 0.f;
          float hf = (float)(__bf16)rv;
          ((__bf16*)Hout)[idx] = (__bf16)(hf * hf);
        }
      }
    }
  }
}

// ==== GEMM2: r15-proven tri-buffered BK=32, A bf16 + B fp32 cvt-on-read ====
template <int K_DIM, int N_DIM, int BN, bool RELU2>
__global__ __launch_bounds__(512, 2)
void ggt(const unsigned short* __restrict__ A,
         const float* __restrict__ Bw,
         const int* __restrict__ counts,
         void* __restrict__ Cout) {
  constexpr int BM = 256, BK = 32;
  constexpr int NT = K_DIM / BK;
  constexpr int WN = BN / 4;
  constexpr int NACC = WN / 16;
  constexpr int BI  = BN / 64;
  constexpr int ISS = 2 + BI;

  const int tid  = threadIdx.x;
  const int wid  = tid >> 6;
  const int lane = tid & 63;
  const int wr   = wid >> 2;
  const int wc   = wid & 3;

  const int id = blockIdx.x + gridDim.x * blockIdx.y;
  const int ct = id & 7;
  const int rt = id >> 3;

  int t = rt;
  int e = -1, rowBase = 0, rowsValid = 0;
  {
    int tiles = 0, off = 0;
#pragma unroll
    for (int i = 0; i < E_NUM; ++i) {
      int n  = counts[i];
      int nt = (n + BM - 1) / BM;
      if (e < 0 && t < tiles + nt) {
        e = i;
        int lt = t - tiles;
        rowBase   = off + lt * BM;
        rowsValid = n - lt * BM;
        if (rowsValid > BM) rowsValid = BM;
      }
      tiles += nt; off += n;
    }
  }
  if (e < 0) return;
  const int colBase = ct * BN;

  __shared__ __align__(1024) char lds[3 * (BM * 64 + BN * 128)];
  auto ldsA = [&](int b) -> char* { return lds + b * (BM * 64); };
  auto ldsB = [&](int b) -> char* { return lds + 3 * (BM * 64) + b * (BN * 128); };

  const char* gA = (const char*)A + (size_t)rowBase * (K_DIM * 2);
  const char* gB = (const char*)Bw + ((size_t)e * N_DIM + colBase) * (size_t)(K_DIM * 4);

  auto stageA = [&](int buf, int kt) {
#pragma unroll
    for (int j = 0; j < 2; ++j) {
      int row0u = j * 128 + wid * 16;
      int r  = row0u + (lane >> 2);
      int sr = (r < rowsValid) ? r : rowsValid - 1;
      int sg = (lane & 3) ^ ((r >> 1) & 3);
      const char* src = gA + (size_t)sr * (K_DIM * 2) + (size_t)kt * 64 + sg * 16;
      __builtin_amdgcn_global_load_lds(
          (const __attribute__((address_space(1))) void*)src,
          (__attribute__((address_space(3))) void*)(ldsA(buf) + row0u * 64),
          16, 0, 0);
    }
  };
  auto stageB = [&](int buf, int kt) {
#pragma unroll
    for (int j = 0; j < BI; ++j) {
      int row0u = j * 64 + wid * 8;
      int r  = row0u + (lane >> 3);
      int sg = (lane & 7) ^ (r & 7);
      const char* src = gB + (size_t)r * (K_DIM * 4) + (size_t)kt * 128 + sg * 16;
      __builtin_amdgcn_global_load_lds(
          (const __attribute__((address_space(1))) void*)src,
          (__attribute__((address_space(3))) void*)(ldsB(buf) + row0u * 128),
          16, 0, 0);
    }
  };

  const int rl = lane & 15;
  const int gh = lane >> 4;

  bf16x8 aF[8], bF[NACC];
  f32x4  accC[8][NACC];
#pragma unroll
  for (int m = 0; m < 8; ++m)
#pragma unroll
    for (int n = 0; n < NACC; ++n) accC[m][n] = (f32x4){0.f, 0.f, 0.f, 0.f};

  auto readA = [&](int buf) {
    const char* base = ldsA(buf);
#pragma unroll
    for (int m = 0; m < 8; ++m) {
      int r = wr * 128 + m * 16 + rl;
      int g = gh ^ ((r >> 1) & 3);
      aF[m] = *(const bf16x8*)(base + r * 64 + g * 16);
    }
  };
  auto readB = [&](int buf) {
    const char* base = ldsB(buf);
#pragma unroll
    for (int n = 0; n < NACC; ++n) {
      int r = wc * WN + n * 16 + rl;
      const char* rb = base + r * 128;
      f32x4 v0 = *(const f32x4*)(rb + (((2 * gh + 0) ^ (r & 7)) * 16));
      f32x4 v1 = *(const f32x4*)(rb + (((2 * gh + 1) ^ (r & 7)) * 16));
      union { __bf16 b[8]; bf16x8 v; } u;
#pragma unroll
      for (int p = 0; p < 4; ++p) {
        u.b[p]     = (__bf16)v0[p];
        u.b[4 + p] = (__bf16)v1[p];
      }
      bF[n] = u.v;
    }
  };

  stageA(0, 0); stageB(0, 0);
  stageA(1, 1); stageB(1, 1);

  for (int t2 = 0; t2 < NT; ++t2) {
    WAIT_VM(ISS);
    BARRIER();
    const int ks = (t2 + 2 < NT) ? t2 + 2 : NT - 1;
    const int bs = (t2 + 2) % 3;
    const int bc = t2 % 3;
    stageA(bs, ks);
    stageB(bs, ks);
    readA(bc);
    readB(bc);
    WAIT_LGKM0();
    __builtin_amdgcn_s_setprio(1);
#pragma unroll
    for (int m = 0; m < 8; ++m)
#pragma unroll
      for (int n = 0; n < NACC; ++n)
        accC[m][n] = __builtin_amdgcn_mfma_f32_16x16x32_bf16(
            aF[m], bF[n], accC[m][n], 0, 0, 0);
    __builtin_amdgcn_s_setprio(0);
  }
  WAIT_VM(0);

  const int rB0 = wr * 128 + gh * 4;
  const int cB0 = colBase + wc * WN + rl;
#pragma unroll
  for (int m = 0; m < 8; ++m) {
#pragma unroll
    for (int n = 0; n < NACC; ++n) {
#pragma unroll
      for (int j = 0; j < 4; ++j) {
        int r = rB0 + m * 16 + j;
        if (r < rowsValid) {
          size_t idx = (size_t)(rowBase + r) * N_DIM + (cB0 + n * 16);
          float v = accC[m][n][j];
          if (RELU2) {
            float rv = v > 0.f ? v : 0.f;
            float hf = (float)(__bf16)rv;
            ((__bf16*)Cout)[idx] = (__bf16)(hf * hf);
          } else {
            ((float*)Cout)[idx] = (float)(__bf16)v;
          }
        }
      }
    }
  }
}

extern "C" void kernel_launch(void* const* d_in, const int* in_sizes, int n_in,
                              void* d_out, int out_size, void* d_ws, size_t ws_size,
                              hipStream_t stream) {
  const float* x   = (const float*)d_in[0];
  const int*   cnt = (const int*)d_in[1];
  const float* wu  = (const float*)d_in[2];
  const float* wd  = (const float*)d_in[3];
  float* out = (float*)d_out;
  char*  ws  = (char*)d_ws;

  unsigned short* hbuf = (unsigned short*)(ws);   // 32 MiB

  // GEMM1: fully fused (x fp32 + w_up fp32, cvt-on-read); grid 40x8
  ggx<<<dim3(40, H_DIM / 256), dim3(512), 0, stream>>>(x, wu, cnt, hbuf);

  // GEMM2: r15-proven path (hbuf bf16 + w_down fp32 cvt-on-read); grid 40x8
  ggt<H_DIM, D_DIM, 128, false><<<dim3(40, D_DIM / 128), dim3(512), 0, stream>>>(
      hbuf, wd, cnt, (void*)out);
}